// Round 4
// baseline (392.031 us; speedup 1.0000x reference)
//
#include <hip/hip_runtime.h>
#include <stdint.h>

// Hamming distance as an i8 MFMA GEMM, 256x256-tile 4-phase counted-vmcnt
// pipeline (T1+T3+T4+T5 from the 8-phase template).
// Encoding: token t -> 3 i8 features (s1, s0, s1*s0), s=+-1.
// dot = 4*matches - 512  =>  dist = 512 - ((dot+512)>>2). Exact in i32.
//
// Packed operand layout == LDS tile layout (so staging is linear & coalesced):
//   pk[R(32)][kt(12)][s(4)][g(2)][r(256)][16B]
// where feature-K byte index kb = kt*128 + s*32 + g*16 + b, global row = R*256+r.
// Seg-major [g][r][16B] makes frag ds_read_b128 2-way bank-aliased (free).

#define NROWS 8192
#define NTOK  512
#define KBYT  1536
#define BM    256
#define KT    12            // K-tiles of 128 bytes
#define THREADS 512

typedef int v4i  __attribute__((ext_vector_type(4)));
typedef int v16i __attribute__((ext_vector_type(16)));

#define AS1(p) ((const __attribute__((address_space(1))) void*)(p))
#define AS3(p) ((__attribute__((address_space(3))) void*)(p))

// ---------------- pack: tokens -> features in tile-slice-major layout -------
__global__ __launch_bounds__(256) void pack_kernel(
    const int* __restrict__ xq, const int* __restrict__ xp,
    uint8_t* __restrict__ qpk, uint8_t* __restrict__ ppk) {
  const int bid = blockIdx.x;            // 3072 = 32R * 12kt * 8sg
  const int sg  = bid & 7;               // s*2+g
  const int rest = bid >> 3;
  const int kt  = rest % 12;
  const int R   = rest / 12;
  const int r   = threadIdx.x;           // 0..255

  const int kb0 = kt * 128 + sg * 16;    // K-byte base of this 16B seg
  const int c   = kb0 >> 9;              // feature index 0..2
  const int d0  = kb0 & 511;             // token index base
  const int row = R * 256 + r;

  const int4* qv = (const int4*)(xq + (size_t)row * NTOK + d0);
  const int4* pv = (const int4*)(xp + (size_t)row * NTOK + d0);

  uint32_t qw[4], pw[4];
  #pragma unroll
  for (int i = 0; i < 4; ++i) {
    int4 a = qv[i], b = pv[i];
    int ta[4] = {a.x, a.y, a.z, a.w};
    int tb[4] = {b.x, b.y, b.z, b.w};
    uint32_t wq = 0, wp = 0;
    #pragma unroll
    for (int j = 0; j < 4; ++j) {
      int bq = (c == 0) ? ((ta[j] >> 1) & 1) : (c == 1) ? (ta[j] & 1)
                        : (((ta[j] >> 1) ^ ta[j]) & 1);
      int bp = (c == 0) ? ((tb[j] >> 1) & 1) : (c == 1) ? (tb[j] & 1)
                        : (((tb[j] >> 1) ^ tb[j]) & 1);
      wq |= (uint32_t)((uint8_t)(1 - 2 * bq)) << (8 * j);
      wp |= (uint32_t)((uint8_t)(1 - 2 * bp)) << (8 * j);
    }
    qw[i] = wq; pw[i] = wp;
  }
  const size_t off = ((size_t)bid * 256 + r) * 16;
  *(uint4*)(qpk + off) = make_uint4(qw[0], qw[1], qw[2], qw[3]);
  *(uint4*)(ppk + off) = make_uint4(pw[0], pw[1], pw[2], pw[3]);
}

// ---------------- main GEMM -------------------------------------------------
__global__ __launch_bounds__(THREADS) void hamming_mfma(
    const uint8_t* __restrict__ Apk, const uint8_t* __restrict__ Bpk,
    int* __restrict__ out) {
  // [buf(2)][op(2)][slice(4)][g(2)][256][16] = 131072 B
  __shared__ __align__(128) uint8_t lds[131072];

  const int t = threadIdx.x;
  const int l = t & 63;
  const int w = t >> 6;                  // 0..7
  const int wr = w >> 2, wc = w & 3;     // wave -> 128x64 output sub-tile

  // XCD-bijective swizzle (1024 blocks, 1024%8==0)
  const int bid = blockIdx.x;
  const int nid = (bid & 7) * 128 + (bid >> 3);
  const int br = nid >> 5, bc = nid & 31;

  const uint8_t* Abase = Apk + (size_t)br * (KT * 4 * 8192);
  const uint8_t* Bbase = Bpk + (size_t)bc * (KT * 4 * 8192);

  const int stoff = w * 1024 + l * 16;   // staging chunk offset (linear)
  const int g4   = (l >> 5) * 4096;      // frag K-half select
  const int arow = (l & 31) * 16;        // frag row byte offset

  v16i acc[4][2] = {};

  // prologue: stage all 4 slices of tile 0 into buf0 (8 insts in flight)
  #pragma unroll
  for (int p = 0; p < 4; ++p) {
    __builtin_amdgcn_global_load_lds(AS1(Abase + p * 8192 + stoff),
                                     AS3(lds + p * 8192 + stoff), 16, 0, 0);
    __builtin_amdgcn_global_load_lds(AS1(Bbase + p * 8192 + stoff),
                                     AS3(lds + 32768 + p * 8192 + stoff), 16, 0, 0);
  }

  for (int kk = 0; kk < KT; ++kk) {
    const int cur = kk & 1;
    const int ktn = (kk + 1 == KT) ? 0 : kk + 1;   // wrap: uniform vmcnt flow
    const uint8_t* an = Abase + (size_t)ktn * (4 * 8192);
    const uint8_t* bn = Bbase + (size_t)ktn * (4 * 8192);
    uint8_t* ldsc = lds + cur * 65536;
    uint8_t* ldsn = lds + (cur ^ 1) * 65536;

    #pragma unroll
    for (int p = 0; p < 4; ++p) {
      // retire exactly slice p of tile kk (FIFO: 8 -> 6 outstanding)
      asm volatile("s_waitcnt vmcnt(6)" ::: "memory");
      __builtin_amdgcn_s_barrier();
      // issue slice p of tile kk+1 into the other buffer (6 -> 8)
      __builtin_amdgcn_global_load_lds(AS1(an + p * 8192 + stoff),
                                       AS3(ldsn + p * 8192 + stoff), 16, 0, 0);
      __builtin_amdgcn_global_load_lds(AS1(bn + p * 8192 + stoff),
                                       AS3(ldsn + 32768 + p * 8192 + stoff), 16, 0, 0);
      // fragment reads for K-slice p (6 x ds_read_b128, 2-way banks = free)
      const uint8_t* ab = ldsc + p * 8192 + g4;
      const uint8_t* bb = ldsc + 32768 + p * 8192 + g4;
      v4i af[4], bf[2];
      #pragma unroll
      for (int m = 0; m < 4; ++m)
        af[m] = *(const v4i*)(ab + (wr * 128 + m * 32) * 16 + arow);
      #pragma unroll
      for (int n = 0; n < 2; ++n)
        bf[n] = *(const v4i*)(bb + (wc * 64 + n * 32) * 16 + arow);
      asm volatile("s_waitcnt lgkmcnt(0)" ::: "memory");
      __builtin_amdgcn_sched_barrier(0);
      __builtin_amdgcn_s_setprio(1);
      #pragma unroll
      for (int m = 0; m < 4; ++m)
        #pragma unroll
        for (int n = 0; n < 2; ++n)
          acc[m][n] = __builtin_amdgcn_mfma_i32_32x32x32_i8(af[m], bf[n],
                                                            acc[m][n], 0, 0, 0);
      __builtin_amdgcn_s_setprio(0);
      __builtin_amdgcn_s_barrier();
    }
  }
  asm volatile("s_waitcnt vmcnt(0)" ::: "memory");

  // epilogue: C/D layout (32x32): col = l&31, row = (reg&3) + 8*(reg>>2) + 4*(l>>5)
  const int rbase = br * BM + wr * 128 + 4 * (l >> 5);
  const int cbase = bc * BM + wc * 64 + (l & 31);
  #pragma unroll
  for (int m = 0; m < 4; ++m)
    #pragma unroll
    for (int n = 0; n < 2; ++n) {
      const int col = cbase + n * 32;
      #pragma unroll
      for (int reg = 0; reg < 16; ++reg) {
        const int orow = rbase + m * 32 + (reg & 3) + 8 * (reg >> 2);
        out[(size_t)orow * NROWS + col] = NTOK - ((acc[m][n][reg] + 512) >> 2);
      }
    }
}

extern "C" void kernel_launch(void* const* d_in, const int* in_sizes, int n_in,
                              void* d_out, int out_size, void* d_ws, size_t ws_size,
                              hipStream_t stream) {
  const int* xq = (const int*)d_in[0];
  const int* xp = (const int*)d_in[1];
  int* out = (int*)d_out;

  uint8_t* qpk = (uint8_t*)d_ws;                        // 12 MB
  uint8_t* ppk = qpk + (size_t)NROWS * KBYT;            // 12 MB

  pack_kernel<<<3072, 256, 0, stream>>>(xq, xp, qpk, ppk);
  hamming_mfma<<<1024, THREADS, 0, stream>>>(qpk, ppk, out);
}

// Round 6
// 322.690 us; speedup vs baseline: 1.2149x; 1.2149x over previous
//
#include <hip/hip_runtime.h>
#include <stdint.h>

// Hamming distance as an MX-FP4 MFMA GEMM (mfma_scale_f32_32x32x64_f8f6f4).
// Token t -> 3 features (s1, s0, s1*s0), s=+-1, encoded as fp4 e2m1 (+1=0x2,
// -1=0xA), scales = 1.0 (0x7F). dot = 4*matches - 512 (exact in f32, |dot|<=1536)
// => dist = 512 - ((dot+512)>>2).
//
// Packed layout == LDS layout (linear staging): pk[R(32)][kt(6)][sg(8)][r(256)][16B]
// where elem e = kt*256 + sg*32 + nibble, feature c = e/512, token d = e%512.

#define NROWS 8192
#define THREADS 512

typedef int   v4i  __attribute__((ext_vector_type(4)));
typedef int   v8i  __attribute__((ext_vector_type(8)));
typedef float v16f __attribute__((ext_vector_type(16)));

#define AS1(p) ((const __attribute__((address_space(1))) void*)(p))
#define AS3(p) ((__attribute__((address_space(3))) void*)(p))

// ---------------- pack: coalesced read, LDS transpose, coalesced write ------
// block = (R64, dhalf, op): 64 rows x 256 tokens -> 3 features -> 3 K-tiles.
__global__ __launch_bounds__(512) void pack_kernel(
    const int* __restrict__ xq, const int* __restrict__ xp,
    uint8_t* __restrict__ qpk, uint8_t* __restrict__ ppk) {
  __shared__ uint8_t lt[64 * 384];      // [rl(64)][c(3)][chunk(8)^swz][16B]
  const int bid = blockIdx.x;           // 512 = 128 R64 * 2 dh * 2 op
  const int op  = bid & 1;
  const int dh  = (bid >> 1) & 1;
  const int R64 = bid >> 2;
  const int t   = threadIdx.x;
  const int* src = op ? xp : xq;
  uint8_t*   dst = op ? ppk : qpk;
  const int row0 = R64 * 64;
  const int d0   = dh * 256;

  #pragma unroll
  for (int i = 0; i < 8; ++i) {
    const int idx = i * 512 + t;        // 64 rows * 64 int4-chunks
    const int rl = idx >> 6, q = idx & 63;
    const int4 a = ((const int4*)(src + (size_t)(row0 + rl) * 512 + d0))[q];
    const int tok[4] = {a.x, a.y, a.z, a.w};
    uint32_t n0 = 0, n1 = 0, n2 = 0;    // 4 nibbles each (fp4: +1=0x2, -1=0xA)
    #pragma unroll
    for (int j = 0; j < 4; ++j) {
      const uint32_t b1 = (tok[j] >> 1) & 1, b0 = tok[j] & 1;
      n0 |= (0x2u | (b1 << 3)) << (4 * j);
      n1 |= (0x2u | (b0 << 3)) << (4 * j);
      n2 |= (0x2u | ((b1 ^ b0) << 3)) << (4 * j);
    }
    uint8_t* p = lt + rl * 384 + (((q >> 3) ^ (rl & 7)) << 4) + (q & 7) * 2;
    *(uint16_t*)(p)       = (uint16_t)n0;
    *(uint16_t*)(p + 128) = (uint16_t)n1;
    *(uint16_t*)(p + 256) = (uint16_t)n2;
  }
  __syncthreads();

  const size_t Rg = R64 >> 2;
  const int rb = (R64 & 3) * 64;
  #pragma unroll
  for (int i = 0; i < 3; ++i) {
    const int o = i * 512 + t;          // 3c * 8sg * 64rl
    const int c = o >> 9, sg = (o >> 6) & 7, rl = o & 63;
    const int kt = c * 2 + dh;
    const uint4 v = *(const uint4*)(lt + rl * 384 + c * 128 + ((sg ^ (rl & 7)) << 4));
    *(uint4*)(dst + (((Rg * 6 + kt) * 8 + sg) * 256 + rb + rl) * 16) = v;
  }
}

// ---------------- main GEMM: 256x256 tile, 6 K-tiles x 4 phases, cnt-vmcnt --
__global__ __launch_bounds__(THREADS, 2) void hamming_mfma(
    const uint8_t* __restrict__ Apk, const uint8_t* __restrict__ Bpk,
    int* __restrict__ out) {
  // [buf(2)][op(2)][slice(4)][g(2)][r(256)][16B] = 128 KiB
  __shared__ __align__(128) uint8_t lds[131072];

  const int t = threadIdx.x, l = t & 63, w = t >> 6;
  const int wr = w >> 2, wc = w & 3;           // wave -> 128x64 output sub-tile

  const int bid = blockIdx.x;                  // XCD-bijective (1024 % 8 == 0)
  const int nid = (bid & 7) * 128 + (bid >> 3);
  const int br = nid >> 5, bc = nid & 31;

  const uint8_t* Abase = Apk + (size_t)br * 196608;   // 6 tiles * 32 KiB
  const uint8_t* Bbase = Bpk + (size_t)bc * 196608;

  const int stoff = w * 1024 + l * 16;         // linear staging chunk
  const int g4   = (l >> 5) * 4096;
  const int aoff = g4 + wr * 2048 + (l & 31) * 16;
  const int boff = g4 + wc * 1024 + (l & 31) * 16;

  v16f acc[4][2] = {};

  // prologue: tile 0, 4 slices x 2 ops (8 loads in flight per wave)
  #pragma unroll
  for (int p = 0; p < 4; ++p) {
    __builtin_amdgcn_global_load_lds(AS1(Abase + p * 8192 + stoff),
                                     AS3(lds + p * 8192 + stoff), 16, 0, 0);
    __builtin_amdgcn_global_load_lds(AS1(Bbase + p * 8192 + stoff),
                                     AS3(lds + 32768 + p * 8192 + stoff), 16, 0, 0);
  }

  for (int kk = 0; kk < 6; ++kk) {
    const int cur = kk & 1;
    const int ktn = (kk == 5) ? 0 : kk + 1;    // wrap keeps vmcnt flow uniform
    const uint8_t* an = Abase + ktn * 32768;
    const uint8_t* bn = Bbase + ktn * 32768;
    uint8_t* ldsc = lds + cur * 65536;
    uint8_t* ldsn = lds + (cur ^ 1) * 65536;

    #pragma unroll
    for (int p = 0; p < 4; ++p) {
      asm volatile("s_waitcnt vmcnt(6)" ::: "memory");   // retire slice p, tile kk
      __builtin_amdgcn_s_barrier();
      __builtin_amdgcn_global_load_lds(AS1(an + p * 8192 + stoff),
                                       AS3(ldsn + p * 8192 + stoff), 16, 0, 0);
      __builtin_amdgcn_global_load_lds(AS1(bn + p * 8192 + stoff),
                                       AS3(ldsn + 32768 + p * 8192 + stoff), 16, 0, 0);
      const uint8_t* ab = ldsc + p * 8192;
      const uint8_t* bb = ldsc + 32768 + p * 8192;
      v4i af[4], bf[2];
      #pragma unroll
      for (int m = 0; m < 4; ++m) af[m] = *(const v4i*)(ab + aoff + m * 512);
      #pragma unroll
      for (int n = 0; n < 2; ++n) bf[n] = *(const v4i*)(bb + boff + n * 512);
      asm volatile("s_waitcnt lgkmcnt(0)" ::: "memory");
      __builtin_amdgcn_sched_barrier(0);
      __builtin_amdgcn_s_setprio(1);
      #pragma unroll
      for (int m = 0; m < 4; ++m)
        #pragma unroll
        for (int n = 0; n < 2; ++n) {
          const v8i av = (v8i){af[m][0], af[m][1], af[m][2], af[m][3], 0, 0, 0, 0};
          const v8i bv = (v8i){bf[n][0], bf[n][1], bf[n][2], bf[n][3], 0, 0, 0, 0};
          acc[m][n] = __builtin_amdgcn_mfma_scale_f32_32x32x64_f8f6f4(
              av, bv, acc[m][n], 4 /*fp4 A*/, 4 /*fp4 B*/,
              0, 0x7F7F7F7F, 0, 0x7F7F7F7F);
        }
      __builtin_amdgcn_s_setprio(0);
      __builtin_amdgcn_s_barrier();
    }
  }
  asm volatile("s_waitcnt vmcnt(0)" ::: "memory");

  // epilogue: C/D (32x32): col = l&31, row = (reg&3) + 8*(reg>>2) + 4*(l>>5)
  const int rbase = br * 256 + wr * 128 + 4 * (l >> 5);
  const int cbase = bc * 256 + wc * 64 + (l & 31);
  #pragma unroll
  for (int m = 0; m < 4; ++m)
    #pragma unroll
    for (int n = 0; n < 2; ++n) {
      const int col = cbase + n * 32;
      #pragma unroll
      for (int reg = 0; reg < 16; ++reg) {
        const int orow = rbase + m * 32 + (reg & 3) + 8 * (reg >> 2);
        out[(size_t)orow * NROWS + col] = 512 - (((int)acc[m][n][reg] + 512) >> 2);
      }
    }
}

extern "C" void kernel_launch(void* const* d_in, const int* in_sizes, int n_in,
                              void* d_out, int out_size, void* d_ws, size_t ws_size,
                              hipStream_t stream) {
  const int* xq = (const int*)d_in[0];
  const int* xp = (const int*)d_in[1];
  int* out = (int*)d_out;

  uint8_t* qpk = (uint8_t*)d_ws;                       // 6 MB
  uint8_t* ppk = qpk + (size_t)NROWS * 768;            // 6 MB

  pack_kernel<<<512, 512, 0, stream>>>(xq, xp, qpk, ppk);
  hamming_mfma<<<1024, THREADS, 0, stream>>>(qpk, ppk, out);
}